// Round 5
// baseline (520.814 us; speedup 1.0000x reference)
//
#include <hip/hip_runtime.h>
#include <hip/hip_bf16.h>
#include <math.h>

#define NPTS 100000
#define KOFF 27

typedef __attribute__((ext_vector_type(8))) __bf16 bf16x8;
typedef __attribute__((ext_vector_type(4))) float f32x4;
typedef __attribute__((ext_vector_type(4))) int i32x4;

__device__ __forceinline__ unsigned short f2bf(float f) {
    unsigned int u = __float_as_uint(f);
    u += 0x7fffu + ((u >> 16) & 1u);   // RNE
    return (unsigned short)(u >> 16);
}

__device__ __forceinline__ float gelu_erf(float v) {
    return 0.5f * v * (1.0f + erff(v * 0.70710678118654752f));
}

// ---------------------------------------------------------------------------
// Kernel 0: repack W1/W2 (fp32 -> bf16) into per-lane MFMA B-fragment order,
// and sniff mask dtype (bool bytes vs int32) into *flagp.
// ---------------------------------------------------------------------------
__global__ __launch_bounds__(256)
void repack_kernel(const float* __restrict__ W1, const float* __restrict__ W2,
                   const void* __restrict__ maskp,
                   unsigned short* __restrict__ W1p,
                   unsigned short* __restrict__ W2p,
                   int* __restrict__ flagp) {
    int o = blockIdx.x * 256 + threadIdx.x;
    if (o == 0) {
        const unsigned int* mw = (const unsigned int*)maskp;
        int f = 0;
        for (int i = 0; i < 64; ++i) f |= (mw[i] > 1u) ? 1 : 0;
        *flagp = f;   // 1 => byte/bool mask, 0 => int32 mask
    }
    if (o < KOFF * 32 * 128) {
        int j = o & 7, lane = (o >> 3) & 63;
        int quad = lane >> 4, nn = lane & 15;
        int ct1 = (o >> 9) & 7, k1 = o >> 12;
        int kk1 = quad * 8 + j;
        W1p[o] = f2bf(W1[(k1 * 32 + kk1) * 128 + (ct1 * 16 + nn)]);
        int ct2 = (o >> 9) & 1, kc2 = (o >> 10) & 3, k2 = o >> 12;
        int kk2 = kc2 * 32 + quad * 8 + j;
        W2p[o] = f2bf(W2[(k2 * 128 + kk2) * 32 + (ct2 * 16 + nn)]);
    }
}

// ---------------------------------------------------------------------------
// Kernel 1: out0 = bf16( gelu( LN( x @ W_conv ) ) )   [N,32]
// ---------------------------------------------------------------------------
__global__ __launch_bounds__(256)
void conv1_ln_gelu(const float* __restrict__ x, const float* __restrict__ Wc,
                   const float* __restrict__ g0, const float* __restrict__ b0,
                   unsigned short* __restrict__ out0) {
    __shared__ float xs[256];
    __shared__ float wc[1024];
    int t = threadIdx.x;
    int nb = blockIdx.x * 8;
    xs[t] = x[nb * 32 + t];
    for (int i = t; i < 1024; i += 256) wc[i] = Wc[i];
    __syncthreads();
    int r = t >> 5, d = t & 31;
    const float* xr = &xs[r * 32];
    float v = 0.f;
#pragma unroll
    for (int c = 0; c < 32; ++c) v = fmaf(xr[c], wc[c * 32 + d], v);
    float s = v, s2 = v * v;
#pragma unroll
    for (int m = 16; m >= 1; m >>= 1) {
        s  += __shfl_xor(s,  m, 32);
        s2 += __shfl_xor(s2, m, 32);
    }
    float mu  = s * (1.f / 32.f);
    float var = s2 * (1.f / 32.f) - mu * mu;
    float y = (v - mu) * rsqrtf(var + 1e-6f) * g0[d] + b0[d];
    out0[nb * 32 + t] = f2bf(gelu_erf(y));
}

// ---------------------------------------------------------------------------
// Stage gather indices for 64 rows into LDS (-1 = masked/tail, skip load).
// ---------------------------------------------------------------------------
__device__ __forceinline__ void stage_gidx64(int* s_gidx, const int* nidx,
                                             const void* maskp, int mflag,
                                             int nb, int t) {
    int cnt = (NPTS - nb < 64 ? NPTS - nb : 64) * KOFF;
    for (int i = t; i < 64 * KOFF; i += 64) {
        int g = -1;
        if (i < cnt) {
            int gi = nidx[nb * KOFF + i];
            int m = mflag ? (int)((const unsigned char*)maskp)[nb * KOFF + i]
                          : ((const int*)maskp)[nb * KOFF + i];
            g = m ? gi : -1;
        }
        s_gidx[i] = g;
    }
}

// ---------------------------------------------------------------------------
// Kernel 2: out1 = bf16( gelu( LN( sparse_conv(out0, W1) ) ) )   [N,128]
// (unchanged from round 4 — rows are 64B = already 1 transaction/row)
// ---------------------------------------------------------------------------
__global__ __launch_bounds__(64, 2)
void conv_k1(const int* __restrict__ nidx, const void* __restrict__ maskp,
             const int* __restrict__ flagp,
             const unsigned short* __restrict__ out0,
             const unsigned short* __restrict__ W1p,
             const float* __restrict__ g1, const float* __restrict__ b1,
             unsigned short* __restrict__ out1) {
    __shared__ int s_gidx[64 * KOFF];

    int t = threadIdx.x;
    int nb = blockIdx.x * 64;
    int mflag = *flagp;
    stage_gidx64(s_gidx, nidx, maskp, mflag, nb, t);
    __syncthreads();

    int lane = t & 63;
    int mrow = lane & 15, quad = lane >> 4;
    const unsigned short* a_base = out0 + quad * 8;
    const int* gp0 = &s_gidx[(0 * 16 + mrow) * KOFF];
    const int* gp1 = &s_gidx[(1 * 16 + mrow) * KOFF];
    const int* gp2 = &s_gidx[(2 * 16 + mrow) * KOFF];
    const int* gp3 = &s_gidx[(3 * 16 + mrow) * KOFF];

    f32x4 acc[4][8] = {};
    bf16x8 a[2][4], b[2][8];

    {
        const unsigned short* wb = W1p + (lane << 3);
#pragma unroll
        for (int ct = 0; ct < 8; ++ct)
            b[0][ct] = *reinterpret_cast<const bf16x8*>(wb + ((ct * 64) << 3));
        int g0 = gp0[0], g1i = gp1[0], g2 = gp2[0], g3 = gp3[0];
        a[0][0] = bf16x8{}; if (g0  >= 0) a[0][0] = *reinterpret_cast<const bf16x8*>(a_base + g0  * 32);
        a[0][1] = bf16x8{}; if (g1i >= 0) a[0][1] = *reinterpret_cast<const bf16x8*>(a_base + g1i * 32);
        a[0][2] = bf16x8{}; if (g2  >= 0) a[0][2] = *reinterpret_cast<const bf16x8*>(a_base + g2  * 32);
        a[0][3] = bf16x8{}; if (g3  >= 0) a[0][3] = *reinterpret_cast<const bf16x8*>(a_base + g3  * 32);
    }

#pragma unroll
    for (int k = 0; k < KOFF; ++k) {
        int cur = k & 1, nxt = cur ^ 1;
        if (k + 1 < KOFF) {
            const unsigned short* wb = W1p + ((((k + 1) * 8) * 64 + lane) << 3);
#pragma unroll
            for (int ct = 0; ct < 8; ++ct)
                b[nxt][ct] = *reinterpret_cast<const bf16x8*>(wb + ((ct * 64) << 3));
            int g0 = gp0[k + 1], g1i = gp1[k + 1], g2 = gp2[k + 1], g3 = gp3[k + 1];
            a[nxt][0] = bf16x8{}; if (g0  >= 0) a[nxt][0] = *reinterpret_cast<const bf16x8*>(a_base + g0  * 32);
            a[nxt][1] = bf16x8{}; if (g1i >= 0) a[nxt][1] = *reinterpret_cast<const bf16x8*>(a_base + g1i * 32);
            a[nxt][2] = bf16x8{}; if (g2  >= 0) a[nxt][2] = *reinterpret_cast<const bf16x8*>(a_base + g2  * 32);
            a[nxt][3] = bf16x8{}; if (g3  >= 0) a[nxt][3] = *reinterpret_cast<const bf16x8*>(a_base + g3  * 32);
        }
#pragma unroll
        for (int rt = 0; rt < 4; ++rt)
#pragma unroll
            for (int ct = 0; ct < 8; ++ct)
                acc[rt][ct] = __builtin_amdgcn_mfma_f32_16x16x32_bf16(a[cur][rt], b[cur][ct], acc[rt][ct], 0, 0, 0);
    }

    float gv[8], bv[8];
#pragma unroll
    for (int ct = 0; ct < 8; ++ct) {
        gv[ct] = g1[ct * 16 + mrow];
        bv[ct] = b1[ct * 16 + mrow];
    }
#pragma unroll
    for (int rt = 0; rt < 4; ++rt) {
        int n_base = nb + rt * 16 + quad * 4;
#pragma unroll
        for (int r = 0; r < 4; ++r) {
            float s = 0.f, s2 = 0.f;
#pragma unroll
            for (int ct = 0; ct < 8; ++ct) { float v = acc[rt][ct][r]; s += v; s2 += v * v; }
#pragma unroll
            for (int m = 1; m <= 8; m <<= 1) {
                s  += __shfl_xor(s,  m, 16);
                s2 += __shfl_xor(s2, m, 16);
            }
            float mu = s * (1.f / 128.f);
            float rs = rsqrtf(s2 * (1.f / 128.f) - mu * mu + 1e-6f);
            int n = n_base + r;
            if (n < NPTS) {
#pragma unroll
                for (int ct = 0; ct < 8; ++ct) {
                    float y = (acc[rt][ct][r] - mu) * rs * gv[ct] + bv[ct];
                    out1[n * 128 + ct * 16 + mrow] = f2bf(gelu_erf(y));
                }
            }
        }
    }
}

// ---------------------------------------------------------------------------
// Kernel 3: out = gelu( LN( sparse_conv(out1, W2) ) + x )   [N,32] fp32
// NEW: coalesced row-gather via LDS staging with per-k compaction.
//  - per k: compact masked-in rows -> glist[k][0..cnt) (pad with row 0)
//  - 16 gather instrs/k: 16 lanes fetch one full 256B row contiguously
//    (4 rows per instr -> 128B-granule L2 transactions, 2 per row)
//  - stage into LDS slots (stride 272B to spread banks), double-buffered
//  - fragments read back with ds_read_b128; masked rows read the zero slot
// ---------------------------------------------------------------------------
#define SLOT_STRIDE 272
#define BUF_SZ (65 * SLOT_STRIDE)

__global__ __launch_bounds__(64)
void conv_k2(const int* __restrict__ nidx, const void* __restrict__ maskp,
             const int* __restrict__ flagp,
             const unsigned short* __restrict__ out1,
             const unsigned short* __restrict__ W2p,
             const float* __restrict__ g2, const float* __restrict__ b2,
             const float* __restrict__ x, float* __restrict__ outp) {
    __shared__ int s_gidx[64 * KOFF];
    __shared__ int glist[KOFF][64];             // compacted gather rows (pad g=0)
    __shared__ unsigned char sbyte[KOFF][64];   // row -> slot (64 = zero slot)
    __shared__ unsigned int cpb[KOFF][16];      // packed slots for mrow: rt bytes
    __shared__ __align__(16) char stage[2 * BUF_SZ];

    int t = threadIdx.x;
    int nb = blockIdx.x * 64;
    int mflag = *flagp;

    stage_gidx64(s_gidx, nidx, maskp, mflag, nb, t);
    // zero the zero-slot (slot 64) of both buffers: 2 x 17 chunks
    if (t < 34) {
        int buf = (t >= 17) ? 1 : 0, c = (t >= 17) ? t - 17 : t;
        *reinterpret_cast<i32x4*>(stage + buf * BUF_SZ + 64 * SLOT_STRIDE + c * 16) = i32x4{0, 0, 0, 0};
    }
    __syncthreads();

    // per-k compaction: lane k scans 64 rows serially
    if (t < KOFF) {
        int c = 0;
        for (int r = 0; r < 64; ++r) {
            int g = s_gidx[r * KOFF + t];
            unsigned char sb = 64;
            if (g >= 0) { sb = (unsigned char)c; glist[t][c] = g; ++c; }
            sbyte[t][r] = sb;
        }
        for (int p = c; p < 64; ++p) glist[t][p] = 0;
    }
    __syncthreads();
    for (int i = t; i < KOFF * 16; i += 64) {
        int k = i >> 4, mr = i & 15;
        cpb[k][mr] = (unsigned)sbyte[k][mr]
                   | ((unsigned)sbyte[k][16 + mr] << 8)
                   | ((unsigned)sbyte[k][32 + mr] << 16)
                   | ((unsigned)sbyte[k][48 + mr] << 24);
    }
    __syncthreads();

    int mrow = t & 15, quad = t >> 4;
    int sub = t >> 4, q = t & 15;     // staging role: slot-sub, chunk
    f32x4 acc[4][2] = {};
    i32x4 sreg[16];
    bf16x8 breg[2][8];

    // prologue: gather+stage k=0, load B k=0
    {
#pragma unroll
        for (int j = 0; j < 16; ++j) {
            int g = glist[0][4 * j + sub];
            sreg[j] = *reinterpret_cast<const i32x4*>(out1 + (size_t)g * 128 + q * 8);
        }
        const unsigned short* wb = W2p + (t << 3);
#pragma unroll
        for (int f = 0; f < 8; ++f)
            breg[0][f] = *reinterpret_cast<const bf16x8*>(wb + ((f * 64) << 3));
#pragma unroll
        for (int j = 0; j < 16; ++j)
            *reinterpret_cast<i32x4*>(stage + (4 * j + sub) * SLOT_STRIDE + q * 16) = sreg[j];
    }

#pragma unroll
    for (int k = 0; k < KOFF; ++k) {
        int cur = k & 1, nxt = cur ^ 1;
        if (k + 1 < KOFF) {   // prefetch k+1 gathers + B while MFMA(k) runs
#pragma unroll
            for (int j = 0; j < 16; ++j) {
                int g = glist[k + 1][4 * j + sub];
                sreg[j] = *reinterpret_cast<const i32x4*>(out1 + (size_t)g * 128 + q * 8);
            }
            const unsigned short* wb = W2p + ((((k + 1) * 8) * 64 + t) << 3);
#pragma unroll
            for (int f = 0; f < 8; ++f)
                breg[nxt][f] = *reinterpret_cast<const bf16x8*>(wb + ((f * 64) << 3));
        }
        unsigned wm = cpb[k][mrow];
        const char* base = stage + cur * BUF_SZ + quad * 16;
#pragma unroll
        for (int rt = 0; rt < 4; ++rt) {
            int s = (wm >> (8 * rt)) & 255;
            const char* rowb = base + s * SLOT_STRIDE;
#pragma unroll
            for (int kc = 0; kc < 4; ++kc) {
                bf16x8 af = *reinterpret_cast<const bf16x8*>(rowb + kc * 64);
                acc[rt][0] = __builtin_amdgcn_mfma_f32_16x16x32_bf16(af, breg[cur][kc * 2 + 0], acc[rt][0], 0, 0, 0);
                acc[rt][1] = __builtin_amdgcn_mfma_f32_16x16x32_bf16(af, breg[cur][kc * 2 + 1], acc[rt][1], 0, 0, 0);
            }
        }
        if (k + 1 < KOFF) {
#pragma unroll
            for (int j = 0; j < 16; ++j)
                *reinterpret_cast<i32x4*>(stage + nxt * BUF_SZ + (4 * j + sub) * SLOT_STRIDE + q * 16) = sreg[j];
        }
    }

    // Epilogue: LN(32) + residual + GELU in-register.
    float gv0 = g2[mrow], gv1 = g2[mrow + 16];
    float bv0 = b2[mrow], bv1 = b2[mrow + 16];
#pragma unroll
    for (int rt = 0; rt < 4; ++rt) {
        int n_base = nb + rt * 16 + quad * 4;
#pragma unroll
        for (int r = 0; r < 4; ++r) {
            float v0 = acc[rt][0][r], v1 = acc[rt][1][r];
            float s = v0 + v1, s2 = v0 * v0 + v1 * v1;
#pragma unroll
            for (int m = 1; m <= 8; m <<= 1) {
                s  += __shfl_xor(s,  m, 16);
                s2 += __shfl_xor(s2, m, 16);
            }
            float mu = s * (1.f / 32.f);
            float rs = rsqrtf(s2 * (1.f / 32.f) - mu * mu + 1e-6f);
            int n = n_base + r;
            if (n < NPTS) {
                float y0 = (v0 - mu) * rs * gv0 + bv0 + x[n * 32 + mrow];
                float y1 = (v1 - mu) * rs * gv1 + bv1 + x[n * 32 + mrow + 16];
                outp[n * 32 + mrow]      = gelu_erf(y0);
                outp[n * 32 + mrow + 16] = gelu_erf(y1);
            }
        }
    }
}

// ---------------------------------------------------------------------------
extern "C" void kernel_launch(void* const* d_in, const int* in_sizes, int n_in,
                              void* d_out, int out_size, void* d_ws, size_t ws_size,
                              hipStream_t stream) {
    const float* x    = (const float*)d_in[0];
    const int*   nidx = (const int*)d_in[1];
    const void*  maskp = d_in[2];
    const float* Wc = (const float*)d_in[3];
    const float* g0 = (const float*)d_in[4];
    const float* b0 = (const float*)d_in[5];
    const float* W1 = (const float*)d_in[6];
    const float* g1 = (const float*)d_in[7];
    const float* b1 = (const float*)d_in[8];
    const float* W2 = (const float*)d_in[9];
    const float* g2 = (const float*)d_in[10];
    const float* b2 = (const float*)d_in[11];

    char* ws = (char*)d_ws;
    unsigned short* out0 = (unsigned short*)ws;                    // 6.4 MB
    unsigned short* out1 = (unsigned short*)(ws + 6400000);        // 25.6 MB
    unsigned short* W1p  = (unsigned short*)(ws + 32000000);       // 221 KB
    unsigned short* W2p  = W1p + KOFF * 32 * 128;                  // 221 KB
    int* flagp = (int*)(W2p + KOFF * 128 * 32);

    repack_kernel<<<432, 256, 0, stream>>>(W1, W2, maskp, W1p, W2p, flagp);
    conv1_ln_gelu<<<NPTS / 8, 256, 0, stream>>>(x, Wc, g0, b0, out0);
    conv_k1<<<(NPTS + 63) / 64, 64, 0, stream>>>(nidx, maskp, flagp, out0, W1p, g1, b1, out1);
    conv_k2<<<(NPTS + 63) / 64, 64, 0, stream>>>(nidx, maskp, flagp, out1, W2p, g2, b2, x, (float*)d_out);
}

// Round 6
// 330.285 us; speedup vs baseline: 1.5769x; 1.5769x over previous
//
#include <hip/hip_runtime.h>
#include <hip/hip_bf16.h>
#include <math.h>

#define NPTS 100000
#define KOFF 27

typedef __attribute__((ext_vector_type(8))) __bf16 bf16x8;
typedef __attribute__((ext_vector_type(4))) float f32x4;

__device__ __forceinline__ unsigned short f2bf(float f) {
    unsigned int u = __float_as_uint(f);
    u += 0x7fffu + ((u >> 16) & 1u);   // RNE
    return (unsigned short)(u >> 16);
}

__device__ __forceinline__ float gelu_erf(float v) {
    return 0.5f * v * (1.0f + erff(v * 0.70710678118654752f));
}

// ---------------------------------------------------------------------------
// Kernel 0: repack W1/W2 (fp32 -> bf16) into per-lane MFMA B-fragment order,
// and sniff mask dtype (bool bytes vs int32) into *flagp.
// ---------------------------------------------------------------------------
__global__ __launch_bounds__(256)
void repack_kernel(const float* __restrict__ W1, const float* __restrict__ W2,
                   const void* __restrict__ maskp,
                   unsigned short* __restrict__ W1p,
                   unsigned short* __restrict__ W2p,
                   int* __restrict__ flagp) {
    int o = blockIdx.x * 256 + threadIdx.x;
    if (o == 0) {
        const unsigned int* mw = (const unsigned int*)maskp;
        int f = 0;
        for (int i = 0; i < 64; ++i) f |= (mw[i] > 1u) ? 1 : 0;
        *flagp = f;   // 1 => byte/bool mask, 0 => int32 mask
    }
    if (o < KOFF * 32 * 128) {
        int j = o & 7, lane = (o >> 3) & 63;
        int quad = lane >> 4, nn = lane & 15;
        int ct1 = (o >> 9) & 7, k1 = o >> 12;
        int kk1 = quad * 8 + j;
        W1p[o] = f2bf(W1[(k1 * 32 + kk1) * 128 + (ct1 * 16 + nn)]);
        int ct2 = (o >> 9) & 1, kc2 = (o >> 10) & 3, k2 = o >> 12;
        int kk2 = kc2 * 32 + quad * 8 + j;
        W2p[o] = f2bf(W2[(k2 * 128 + kk2) * 32 + (ct2 * 16 + nn)]);
    }
}

// ---------------------------------------------------------------------------
// Kernel 1: out0 = bf16( gelu( LN( x @ W_conv ) ) )   [N,32]
// ---------------------------------------------------------------------------
__global__ __launch_bounds__(256)
void conv1_ln_gelu(const float* __restrict__ x, const float* __restrict__ Wc,
                   const float* __restrict__ g0, const float* __restrict__ b0,
                   unsigned short* __restrict__ out0) {
    __shared__ float xs[256];
    __shared__ float wc[1024];
    int t = threadIdx.x;
    int nb = blockIdx.x * 8;
    xs[t] = x[nb * 32 + t];
    for (int i = t; i < 1024; i += 256) wc[i] = Wc[i];
    __syncthreads();
    int r = t >> 5, d = t & 31;
    const float* xr = &xs[r * 32];
    float v = 0.f;
#pragma unroll
    for (int c = 0; c < 32; ++c) v = fmaf(xr[c], wc[c * 32 + d], v);
    float s = v, s2 = v * v;
#pragma unroll
    for (int m = 16; m >= 1; m >>= 1) {
        s  += __shfl_xor(s,  m, 32);
        s2 += __shfl_xor(s2, m, 32);
    }
    float mu  = s * (1.f / 32.f);
    float var = s2 * (1.f / 32.f) - mu * mu;
    float y = (v - mu) * rsqrtf(var + 1e-6f) * g0[d] + b0[d];
    out0[nb * 32 + t] = f2bf(gelu_erf(y));
}

// ---------------------------------------------------------------------------
// Stage gather indices for 64 rows into LDS (-1 = masked/tail, skip load).
// Block = 128 threads (two waves).
// ---------------------------------------------------------------------------
__device__ __forceinline__ void stage_gidx128(int* s_gidx, const int* nidx,
                                              const void* maskp, int mflag,
                                              int nb, int t) {
    int cnt = (NPTS - nb < 64 ? NPTS - nb : 64) * KOFF;
    for (int i = t; i < 64 * KOFF; i += 128) {
        int g = -1;
        if (i < cnt) {
            int gi = nidx[nb * KOFF + i];
            int m = mflag ? (int)((const unsigned char*)maskp)[nb * KOFF + i]
                          : ((const int*)maskp)[nb * KOFF + i];
            g = m ? gi : -1;
        }
        s_gidx[i] = g;
    }
}

// ---------------------------------------------------------------------------
// Kernel 2: out1 = bf16( gelu( LN( sparse_conv(out0, W1) ) ) )   [N,128]
// 128-thr blocks (2 waves), 64 rows/block; wave w owns 32 rows (2 row-tiles),
// all 8 col-tiles. B-ring distance 1 (L2-hot), A-ring distance 2 (LLC-latency);
// body issues B(k+1) BEFORE A(k+2) so the vmcnt wait for B(k) keeps
// A(k+1),B(k+1),A(k+2) = 12 loads in flight per wave.
// ---------------------------------------------------------------------------
__global__ __launch_bounds__(128, 3)
void conv_k1(const int* __restrict__ nidx, const void* __restrict__ maskp,
             const int* __restrict__ flagp,
             const unsigned short* __restrict__ out0,
             const unsigned short* __restrict__ W1p,
             const float* __restrict__ g1, const float* __restrict__ b1,
             unsigned short* __restrict__ out1) {
    __shared__ int s_gidx[64 * KOFF];

    int t = threadIdx.x;
    int nb = blockIdx.x * 64;
    int mflag = *flagp;
    stage_gidx128(s_gidx, nidx, maskp, mflag, nb, t);
    __syncthreads();

    int lane = t & 63, w = t >> 6;
    int mrow = lane & 15, quad = lane >> 4;
    const unsigned short* a_base = out0 + quad * 8;
    const int* gp0 = &s_gidx[(w * 32 + 0 * 16 + mrow) * KOFF];
    const int* gp1 = &s_gidx[(w * 32 + 1 * 16 + mrow) * KOFF];

    f32x4 acc[2][8] = {};
    bf16x8 a[3][2], b[2][8];

    // prologue (issue order matters): B(0), A(0), A(1)
    {
        const unsigned short* wb = W1p + (lane << 3);
#pragma unroll
        for (int ct = 0; ct < 8; ++ct)
            b[0][ct] = *reinterpret_cast<const bf16x8*>(wb + ((ct * 64) << 3));
        int g0 = gp0[0], g1i = gp1[0];
        a[0][0] = bf16x8{}; if (g0  >= 0) a[0][0] = *reinterpret_cast<const bf16x8*>(a_base + g0  * 32);
        a[0][1] = bf16x8{}; if (g1i >= 0) a[0][1] = *reinterpret_cast<const bf16x8*>(a_base + g1i * 32);
        g0 = gp0[1]; g1i = gp1[1];
        a[1][0] = bf16x8{}; if (g0  >= 0) a[1][0] = *reinterpret_cast<const bf16x8*>(a_base + g0  * 32);
        a[1][1] = bf16x8{}; if (g1i >= 0) a[1][1] = *reinterpret_cast<const bf16x8*>(a_base + g1i * 32);
    }

#pragma unroll
    for (int k = 0; k < KOFF; ++k) {
        if (k + 1 < KOFF) {   // B(k+1) first
            const unsigned short* wb = W1p + ((((k + 1) * 8) * 64 + lane) << 3);
#pragma unroll
            for (int ct = 0; ct < 8; ++ct)
                b[(k + 1) & 1][ct] = *reinterpret_cast<const bf16x8*>(wb + ((ct * 64) << 3));
        }
        if (k + 2 < KOFF) {   // then A(k+2)
            int g0 = gp0[k + 2], g1i = gp1[k + 2];
            int s = (k + 2) % 3;
            a[s][0] = bf16x8{}; if (g0  >= 0) a[s][0] = *reinterpret_cast<const bf16x8*>(a_base + g0  * 32);
            a[s][1] = bf16x8{}; if (g1i >= 0) a[s][1] = *reinterpret_cast<const bf16x8*>(a_base + g1i * 32);
        }
#pragma unroll
        for (int rt = 0; rt < 2; ++rt)
#pragma unroll
            for (int ct = 0; ct < 8; ++ct)
                acc[rt][ct] = __builtin_amdgcn_mfma_f32_16x16x32_bf16(a[k % 3][rt], b[k & 1][ct], acc[rt][ct], 0, 0, 0);
    }

    // Epilogue: LN(128) + GELU in-register.
    float gv[8], bv[8];
#pragma unroll
    for (int ct = 0; ct < 8; ++ct) {
        gv[ct] = g1[ct * 16 + mrow];
        bv[ct] = b1[ct * 16 + mrow];
    }
#pragma unroll
    for (int rt = 0; rt < 2; ++rt) {
        int n_base = nb + w * 32 + rt * 16 + quad * 4;
#pragma unroll
        for (int r = 0; r < 4; ++r) {
            float s = 0.f, s2 = 0.f;
#pragma unroll
            for (int ct = 0; ct < 8; ++ct) { float v = acc[rt][ct][r]; s += v; s2 += v * v; }
#pragma unroll
            for (int m = 1; m <= 8; m <<= 1) {
                s  += __shfl_xor(s,  m, 16);
                s2 += __shfl_xor(s2, m, 16);
            }
            float mu = s * (1.f / 128.f);
            float rs = rsqrtf(s2 * (1.f / 128.f) - mu * mu + 1e-6f);
            int n = n_base + r;
            if (n < NPTS) {
#pragma unroll
                for (int ct = 0; ct < 8; ++ct) {
                    float y = (acc[rt][ct][r] - mu) * rs * gv[ct] + bv[ct];
                    out1[n * 128 + ct * 16 + mrow] = f2bf(gelu_erf(y));
                }
            }
        }
    }
}

// ---------------------------------------------------------------------------
// Kernel 3: out = gelu( LN( sparse_conv(out1, W2) ) + x )   [N,32] fp32
// 128-thr blocks (2 waves), 64 rows/block; wave w owns 32 rows (2 row-tiles),
// both col-tiles, K=128 (4 kc chunks). Distance-1 rings, A issued before B
// so the wait for B(k) keeps A(k+1)+B(k+1) = 16 loads in flight per wave.
// ---------------------------------------------------------------------------
__global__ __launch_bounds__(128, 3)
void conv_k2(const int* __restrict__ nidx, const void* __restrict__ maskp,
             const int* __restrict__ flagp,
             const unsigned short* __restrict__ out1,
             const unsigned short* __restrict__ W2p,
             const float* __restrict__ g2, const float* __restrict__ b2,
             const float* __restrict__ x, float* __restrict__ outp) {
    __shared__ int s_gidx[64 * KOFF];

    int t = threadIdx.x;
    int nb = blockIdx.x * 64;
    int mflag = *flagp;
    stage_gidx128(s_gidx, nidx, maskp, mflag, nb, t);
    __syncthreads();

    int lane = t & 63, w = t >> 6;
    int mrow = lane & 15, quad = lane >> 4;
    const unsigned short* a_base = out1 + quad * 8;
    const int* gp0 = &s_gidx[(w * 32 + 0 * 16 + mrow) * KOFF];
    const int* gp1 = &s_gidx[(w * 32 + 1 * 16 + mrow) * KOFF];

    f32x4 acc[2][2] = {};
    bf16x8 a[2][2][4], b[2][8];

    // prologue: A(0) then B(0)
    {
        int gg[2] = { gp0[0], gp1[0] };
#pragma unroll
        for (int rt = 0; rt < 2; ++rt) {
#pragma unroll
            for (int kc = 0; kc < 4; ++kc) a[0][rt][kc] = bf16x8{};
            if (gg[rt] >= 0) {
#pragma unroll
                for (int kc = 0; kc < 4; ++kc)
                    a[0][rt][kc] = *reinterpret_cast<const bf16x8*>(a_base + gg[rt] * 128 + kc * 32);
            }
        }
        const unsigned short* wb = W2p + (lane << 3);
#pragma unroll
        for (int f = 0; f < 8; ++f)
            b[0][f] = *reinterpret_cast<const bf16x8*>(wb + ((f * 64) << 3));
    }

#pragma unroll
    for (int k = 0; k < KOFF; ++k) {
        int cur = k & 1, nxt = cur ^ 1;
        if (k + 1 < KOFF) {   // A(k+1) first (long latency), then B(k+1)
            int gg[2] = { gp0[k + 1], gp1[k + 1] };
#pragma unroll
            for (int rt = 0; rt < 2; ++rt) {
#pragma unroll
                for (int kc = 0; kc < 4; ++kc) a[nxt][rt][kc] = bf16x8{};
                if (gg[rt] >= 0) {
#pragma unroll
                    for (int kc = 0; kc < 4; ++kc)
                        a[nxt][rt][kc] = *reinterpret_cast<const bf16x8*>(a_base + gg[rt] * 128 + kc * 32);
                }
            }
            const unsigned short* wb = W2p + ((((k + 1) * 8) * 64 + lane) << 3);
#pragma unroll
            for (int f = 0; f < 8; ++f)
                b[nxt][f] = *reinterpret_cast<const bf16x8*>(wb + ((f * 64) << 3));
        }
#pragma unroll
        for (int rt = 0; rt < 2; ++rt)
#pragma unroll
            for (int kc = 0; kc < 4; ++kc) {
                acc[rt][0] = __builtin_amdgcn_mfma_f32_16x16x32_bf16(a[cur][rt][kc], b[cur][kc * 2 + 0], acc[rt][0], 0, 0, 0);
                acc[rt][1] = __builtin_amdgcn_mfma_f32_16x16x32_bf16(a[cur][rt][kc], b[cur][kc * 2 + 1], acc[rt][1], 0, 0, 0);
            }
    }

    // Epilogue: LN(32) + residual + GELU in-register.
    float gv0 = g2[mrow], gv1 = g2[mrow + 16];
    float bv0 = b2[mrow], bv1 = b2[mrow + 16];
#pragma unroll
    for (int rt = 0; rt < 2; ++rt) {
        int n_base = nb + w * 32 + rt * 16 + quad * 4;
#pragma unroll
        for (int r = 0; r < 4; ++r) {
            float v0 = acc[rt][0][r], v1 = acc[rt][1][r];
            float s = v0 + v1, s2 = v0 * v0 + v1 * v1;
#pragma unroll
            for (int m = 1; m <= 8; m <<= 1) {
                s  += __shfl_xor(s,  m, 16);
                s2 += __shfl_xor(s2, m, 16);
            }
            float mu = s * (1.f / 32.f);
            float rs = rsqrtf(s2 * (1.f / 32.f) - mu * mu + 1e-6f);
            int n = n_base + r;
            if (n < NPTS) {
                float y0 = (v0 - mu) * rs * gv0 + bv0 + x[n * 32 + mrow];
                float y1 = (v1 - mu) * rs * gv1 + bv1 + x[n * 32 + mrow + 16];
                outp[n * 32 + mrow]      = gelu_erf(y0);
                outp[n * 32 + mrow + 16] = gelu_erf(y1);
            }
        }
    }
}

// ---------------------------------------------------------------------------
extern "C" void kernel_launch(void* const* d_in, const int* in_sizes, int n_in,
                              void* d_out, int out_size, void* d_ws, size_t ws_size,
                              hipStream_t stream) {
    const float* x    = (const float*)d_in[0];
    const int*   nidx = (const int*)d_in[1];
    const void*  maskp = d_in[2];
    const float* Wc = (const float*)d_in[3];
    const float* g0 = (const float*)d_in[4];
    const float* b0 = (const float*)d_in[5];
    const float* W1 = (const float*)d_in[6];
    const float* g1 = (const float*)d_in[7];
    const float* b1 = (const float*)d_in[8];
    const float* W2 = (const float*)d_in[9];
    const float* g2 = (const float*)d_in[10];
    const float* b2 = (const float*)d_in[11];

    char* ws = (char*)d_ws;
    unsigned short* out0 = (unsigned short*)ws;                    // 6.4 MB
    unsigned short* out1 = (unsigned short*)(ws + 6400000);        // 25.6 MB
    unsigned short* W1p  = (unsigned short*)(ws + 32000000);       // 221 KB
    unsigned short* W2p  = W1p + KOFF * 32 * 128;                  // 221 KB
    int* flagp = (int*)(W2p + KOFF * 128 * 32);

    repack_kernel<<<432, 256, 0, stream>>>(W1, W2, maskp, W1p, W2p, flagp);
    conv1_ln_gelu<<<NPTS / 8, 256, 0, stream>>>(x, Wc, g0, b0, out0);
    conv_k1<<<(NPTS + 63) / 64, 128, 0, stream>>>(nidx, maskp, flagp, out0, W1p, g1, b1, out1);
    conv_k2<<<(NPTS + 63) / 64, 128, 0, stream>>>(nidx, maskp, flagp, out1, W2p, g2, b2, x, (float*)d_out);
}

// Round 8
// 277.805 us; speedup vs baseline: 1.8747x; 1.1889x over previous
//
#include <hip/hip_runtime.h>
#include <hip/hip_bf16.h>
#include <math.h>

#define NPTS 100000
#define KOFF 27

typedef __attribute__((ext_vector_type(8))) __bf16 bf16x8;
typedef __attribute__((ext_vector_type(4))) float f32x4;

__device__ __forceinline__ unsigned short f2bf(float f) {
    unsigned int u = __float_as_uint(f);
    u += 0x7fffu + ((u >> 16) & 1u);   // RNE
    return (unsigned short)(u >> 16);
}

__device__ __forceinline__ float gelu_erf(float v) {
    return 0.5f * v * (1.0f + erff(v * 0.70710678118654752f));
}

// ---------------------------------------------------------------------------
// Kernel 0: repack W1/W2 (fp32 -> bf16) into per-lane MFMA B-fragment order,
// and sniff mask dtype (bool bytes vs int32) into *flagp.
// ---------------------------------------------------------------------------
__global__ __launch_bounds__(256)
void repack_kernel(const float* __restrict__ W1, const float* __restrict__ W2,
                   const void* __restrict__ maskp,
                   unsigned short* __restrict__ W1p,
                   unsigned short* __restrict__ W2p,
                   int* __restrict__ flagp) {
    int o = blockIdx.x * 256 + threadIdx.x;
    if (o == 0) {
        const unsigned int* mw = (const unsigned int*)maskp;
        int f = 0;
        for (int i = 0; i < 64; ++i) f |= (mw[i] > 1u) ? 1 : 0;
        *flagp = f;   // 1 => byte/bool mask, 0 => int32 mask
    }
    if (o < KOFF * 32 * 128) {
        int j = o & 7, lane = (o >> 3) & 63;
        int quad = lane >> 4, nn = lane & 15;
        int ct1 = (o >> 9) & 7, k1 = o >> 12;
        int kk1 = quad * 8 + j;
        W1p[o] = f2bf(W1[(k1 * 32 + kk1) * 128 + (ct1 * 16 + nn)]);
        int ct2 = (o >> 9) & 1, kc2 = (o >> 10) & 3, k2 = o >> 12;
        int kk2 = kc2 * 32 + quad * 8 + j;
        W2p[o] = f2bf(W2[(k2 * 128 + kk2) * 32 + (ct2 * 16 + nn)]);
    }
}

// ---------------------------------------------------------------------------
// Kernel 1: out0 = bf16( gelu( LN( x @ W_conv ) ) )   [N,32]
// ---------------------------------------------------------------------------
__global__ __launch_bounds__(256)
void conv1_ln_gelu(const float* __restrict__ x, const float* __restrict__ Wc,
                   const float* __restrict__ g0, const float* __restrict__ b0,
                   unsigned short* __restrict__ out0) {
    __shared__ float xs[256];
    __shared__ float wc[1024];
    int t = threadIdx.x;
    int nb = blockIdx.x * 8;
    xs[t] = x[nb * 32 + t];
    for (int i = t; i < 1024; i += 256) wc[i] = Wc[i];
    __syncthreads();
    int r = t >> 5, d = t & 31;
    const float* xr = &xs[r * 32];
    float v = 0.f;
#pragma unroll
    for (int c = 0; c < 32; ++c) v = fmaf(xr[c], wc[c * 32 + d], v);
    float s = v, s2 = v * v;
#pragma unroll
    for (int m = 16; m >= 1; m >>= 1) {
        s  += __shfl_xor(s,  m, 32);
        s2 += __shfl_xor(s2, m, 32);
    }
    float mu  = s * (1.f / 32.f);
    float var = s2 * (1.f / 32.f) - mu * mu;
    float y = (v - mu) * rsqrtf(var + 1e-6f) * g0[d] + b0[d];
    out0[nb * 32 + t] = f2bf(gelu_erf(y));
}

// ---------------------------------------------------------------------------
// Stage gather indices for 64 rows into LDS (-1 = masked/tail, skip load).
// Block = 64 threads (one wave).
// ---------------------------------------------------------------------------
__device__ __forceinline__ void stage_gidx64(int* s_gidx, const int* nidx,
                                             const void* maskp, int mflag,
                                             int nb, int t) {
    int cnt = (NPTS - nb < 64 ? NPTS - nb : 64) * KOFF;
    for (int i = t; i < 64 * KOFF; i += 64) {
        int g = -1;
        if (i < cnt) {
            int gi = nidx[nb * KOFF + i];
            int m = mflag ? (int)((const unsigned char*)maskp)[nb * KOFF + i]
                          : ((const int*)maskp)[nb * KOFF + i];
            g = m ? gi : -1;
        }
        s_gidx[i] = g;
    }
}

// ---------------------------------------------------------------------------
// Kernel 2: out1 = bf16( gelu( LN( sparse_conv(out0, W1) ) ) )   [N,128]
// r4 structure (1 wave/block, 64 rows, 8 col-tiles, depth-1 dual rings).
// ---------------------------------------------------------------------------
__global__ __launch_bounds__(64, 2)
void conv_k1(const int* __restrict__ nidx, const void* __restrict__ maskp,
             const int* __restrict__ flagp,
             const unsigned short* __restrict__ out0,
             const unsigned short* __restrict__ W1p,
             const float* __restrict__ g1, const float* __restrict__ b1,
             unsigned short* __restrict__ out1) {
    __shared__ int s_gidx[64 * KOFF];

    int t = threadIdx.x;
    int nb = blockIdx.x * 64;
    int mflag = *flagp;
    stage_gidx64(s_gidx, nidx, maskp, mflag, nb, t);
    __syncthreads();

    int lane = t & 63;
    int mrow = lane & 15, quad = lane >> 4;
    const unsigned short* a_base = out0 + quad * 8;
    const int* gp0 = &s_gidx[(0 * 16 + mrow) * KOFF];
    const int* gp1 = &s_gidx[(1 * 16 + mrow) * KOFF];
    const int* gp2 = &s_gidx[(2 * 16 + mrow) * KOFF];
    const int* gp3 = &s_gidx[(3 * 16 + mrow) * KOFF];

    f32x4 acc[4][8] = {};
    bf16x8 a[2][4], b[2][8];

    {
        const unsigned short* wb = W1p + (lane << 3);
#pragma unroll
        for (int ct = 0; ct < 8; ++ct)
            b[0][ct] = *reinterpret_cast<const bf16x8*>(wb + ((ct * 64) << 3));
        int g0 = gp0[0], g1i = gp1[0], g2 = gp2[0], g3 = gp3[0];
        a[0][0] = bf16x8{}; if (g0  >= 0) a[0][0] = *reinterpret_cast<const bf16x8*>(a_base + g0  * 32);
        a[0][1] = bf16x8{}; if (g1i >= 0) a[0][1] = *reinterpret_cast<const bf16x8*>(a_base + g1i * 32);
        a[0][2] = bf16x8{}; if (g2  >= 0) a[0][2] = *reinterpret_cast<const bf16x8*>(a_base + g2  * 32);
        a[0][3] = bf16x8{}; if (g3  >= 0) a[0][3] = *reinterpret_cast<const bf16x8*>(a_base + g3  * 32);
    }

#pragma unroll
    for (int k = 0; k < KOFF; ++k) {
        int cur = k & 1, nxt = cur ^ 1;
        if (k + 1 < KOFF) {
            const unsigned short* wb = W1p + ((((k + 1) * 8) * 64 + lane) << 3);
#pragma unroll
            for (int ct = 0; ct < 8; ++ct)
                b[nxt][ct] = *reinterpret_cast<const bf16x8*>(wb + ((ct * 64) << 3));
            int g0 = gp0[k + 1], g1i = gp1[k + 1], g2 = gp2[k + 1], g3 = gp3[k + 1];
            a[nxt][0] = bf16x8{}; if (g0  >= 0) a[nxt][0] = *reinterpret_cast<const bf16x8*>(a_base + g0  * 32);
            a[nxt][1] = bf16x8{}; if (g1i >= 0) a[nxt][1] = *reinterpret_cast<const bf16x8*>(a_base + g1i * 32);
            a[nxt][2] = bf16x8{}; if (g2  >= 0) a[nxt][2] = *reinterpret_cast<const bf16x8*>(a_base + g2  * 32);
            a[nxt][3] = bf16x8{}; if (g3  >= 0) a[nxt][3] = *reinterpret_cast<const bf16x8*>(a_base + g3  * 32);
        }
#pragma unroll
        for (int rt = 0; rt < 4; ++rt)
#pragma unroll
            for (int ct = 0; ct < 8; ++ct)
                acc[rt][ct] = __builtin_amdgcn_mfma_f32_16x16x32_bf16(a[cur][rt], b[cur][ct], acc[rt][ct], 0, 0, 0);
    }

    float gv[8], bv[8];
#pragma unroll
    for (int ct = 0; ct < 8; ++ct) {
        gv[ct] = g1[ct * 16 + mrow];
        bv[ct] = b1[ct * 16 + mrow];
    }
#pragma unroll
    for (int rt = 0; rt < 4; ++rt) {
        int n_base = nb + rt * 16 + quad * 4;
#pragma unroll
        for (int r = 0; r < 4; ++r) {
            float s = 0.f, s2 = 0.f;
#pragma unroll
            for (int ct = 0; ct < 8; ++ct) { float v = acc[rt][ct][r]; s += v; s2 += v * v; }
#pragma unroll
            for (int m = 1; m <= 8; m <<= 1) {
                s  += __shfl_xor(s,  m, 16);
                s2 += __shfl_xor(s2, m, 16);
            }
            float mu = s * (1.f / 128.f);
            float rs = rsqrtf(s2 * (1.f / 128.f) - mu * mu + 1e-6f);
            int n = n_base + r;
            if (n < NPTS) {
#pragma unroll
                for (int ct = 0; ct < 8; ++ct) {
                    float y = (acc[rt][ct][r] - mu) * rs * gv[ct] + bv[ct];
                    out1[n * 128 + ct * 16 + mrow] = f2bf(gelu_erf(y));
                }
            }
        }
    }
}

// ---------------------------------------------------------------------------
// Kernel 3a: tmp[k][n][32] = bf16( out1[n,:] @ W2[k] )  — DENSE, no gathers.
// 1 wave/block, 64 rows; A loaded once (coalesced), B ring depth-1 (L1-hot).
// ---------------------------------------------------------------------------
__global__ __launch_bounds__(64, 2)
void gemm_tmp(const unsigned short* __restrict__ out1,
              const unsigned short* __restrict__ W2p,
              unsigned short* __restrict__ tmp) {
    int t = threadIdx.x;
    int nb = blockIdx.x * 64;
    int mrow = t & 15, quad = t >> 4;

    bf16x8 a[4][4];
#pragma unroll
    for (int rt = 0; rt < 4; ++rt) {
        int n = nb + rt * 16 + mrow;
        bool ok = (n < NPTS);
#pragma unroll
        for (int kc = 0; kc < 4; ++kc) {
            a[rt][kc] = bf16x8{};
            if (ok)
                a[rt][kc] = *reinterpret_cast<const bf16x8*>(out1 + (size_t)n * 128 + kc * 32 + quad * 8);
        }
    }
    bf16x8 b[2][8];
    {
        const unsigned short* wb = W2p + (t << 3);
#pragma unroll
        for (int f = 0; f < 8; ++f)
            b[0][f] = *reinterpret_cast<const bf16x8*>(wb + ((f * 64) << 3));
    }

#pragma unroll
    for (int k = 0; k < KOFF; ++k) {
        int cur = k & 1, nxt = cur ^ 1;
        if (k + 1 < KOFF) {
            const unsigned short* wb = W2p + ((((k + 1) * 8) * 64 + t) << 3);
#pragma unroll
            for (int f = 0; f < 8; ++f)
                b[nxt][f] = *reinterpret_cast<const bf16x8*>(wb + ((f * 64) << 3));
        }
        f32x4 acc[4][2] = {};
#pragma unroll
        for (int rt = 0; rt < 4; ++rt)
#pragma unroll
            for (int kc = 0; kc < 4; ++kc) {
                acc[rt][0] = __builtin_amdgcn_mfma_f32_16x16x32_bf16(a[rt][kc], b[cur][kc * 2 + 0], acc[rt][0], 0, 0, 0);
                acc[rt][1] = __builtin_amdgcn_mfma_f32_16x16x32_bf16(a[rt][kc], b[cur][kc * 2 + 1], acc[rt][1], 0, 0, 0);
            }
        unsigned short* tk = tmp + (size_t)k * NPTS * 32;
#pragma unroll
        for (int rt = 0; rt < 4; ++rt) {
            int n0 = nb + rt * 16 + quad * 4;
#pragma unroll
            for (int r = 0; r < 4; ++r) {
                int n = n0 + r;
                if (n < NPTS) {
#pragma unroll
                    for (int ct = 0; ct < 2; ++ct)
                        tk[(size_t)n * 32 + ct * 16 + mrow] = f2bf(acc[rt][ct][r]);
                }
            }
        }
    }
}

// ---------------------------------------------------------------------------
// Kernel 3b: out = gelu( LN( Σ_k mask·tmp[k][idx[n,k]] ) + x )   [N,32] fp32
// 256-thr blocks, 4 lanes/row (16 B each): one gather instr = 16 full 64 B
// rows = 1 segment/row. Ring depth 3. fp32 accumulate in-register.
// ---------------------------------------------------------------------------
__global__ __launch_bounds__(256)
void gather_sum(const int* __restrict__ nidx, const void* __restrict__ maskp,
                const int* __restrict__ flagp,
                const unsigned short* __restrict__ tmp,
                const float* __restrict__ g2, const float* __restrict__ b2,
                const float* __restrict__ x, float* __restrict__ outp) {
    __shared__ int s_gidx[64 * KOFF];
    int t = threadIdx.x;
    int nb = blockIdx.x * 64;
    int mflag = *flagp;
    int cnt = (NPTS - nb < 64 ? NPTS - nb : 64) * KOFF;
    for (int i = t; i < 64 * KOFF; i += 256) {
        int g = -1;
        if (i < cnt) {
            int gi = nidx[nb * KOFF + i];
            int m = mflag ? (int)((const unsigned char*)maskp)[nb * KOFF + i]
                          : ((const int*)maskp)[nb * KOFF + i];
            g = m ? gi : -1;
        }
        s_gidx[i] = g;
    }
    __syncthreads();

    int rl = t >> 2, q = t & 3;
    const int* gp = &s_gidx[rl * KOFF];
    const unsigned short* tq = tmp + q * 8;

    float acc[8] = {};
    uint4 ring[3];
#pragma unroll
    for (int d = 0; d < 3; ++d) {
        int g = gp[d];
        ring[d] = uint4{0u, 0u, 0u, 0u};
        if (g >= 0)
            ring[d] = *reinterpret_cast<const uint4*>(tq + ((size_t)d * NPTS + g) * 32);
    }
#pragma unroll
    for (int k = 0; k < KOFF; ++k) {
        uint4 v = ring[k % 3];
        if (k + 3 < KOFF) {
            int g = gp[k + 3];
            ring[k % 3] = uint4{0u, 0u, 0u, 0u};
            if (g >= 0)
                ring[k % 3] = *reinterpret_cast<const uint4*>(tq + ((size_t)(k + 3) * NPTS + g) * 32);
        }
        unsigned int w0 = v.x, w1 = v.y, w2 = v.z, w3 = v.w;
        acc[0] += __uint_as_float(w0 << 16);
        acc[1] += __uint_as_float(w0 & 0xffff0000u);
        acc[2] += __uint_as_float(w1 << 16);
        acc[3] += __uint_as_float(w1 & 0xffff0000u);
        acc[4] += __uint_as_float(w2 << 16);
        acc[5] += __uint_as_float(w2 & 0xffff0000u);
        acc[6] += __uint_as_float(w3 << 16);
        acc[7] += __uint_as_float(w3 & 0xffff0000u);
    }

    float s = 0.f, s2 = 0.f;
#pragma unroll
    for (int j = 0; j < 8; ++j) { s += acc[j]; s2 += acc[j] * acc[j]; }
    s += __shfl_xor(s, 1); s2 += __shfl_xor(s2, 1);
    s += __shfl_xor(s, 2); s2 += __shfl_xor(s2, 2);
    float mu = s * (1.f / 32.f);
    float rs = rsqrtf(s2 * (1.f / 32.f) - mu * mu + 1e-6f);

    int n = nb + rl;
    if (n < NPTS) {
        float o[8];
#pragma unroll
        for (int j = 0; j < 8; ++j) {
            int c = q * 8 + j;
            float y = (acc[j] - mu) * rs * g2[c] + b2[c] + x[n * 32 + c];
            o[j] = gelu_erf(y);
        }
        *reinterpret_cast<float4*>(outp + n * 32 + q * 8)     = make_float4(o[0], o[1], o[2], o[3]);
        *reinterpret_cast<float4*>(outp + n * 32 + q * 8 + 4) = make_float4(o[4], o[5], o[6], o[7]);
    }
}

// ---------------------------------------------------------------------------
// Fallback Kernel 3 (r4): gather-GEMM conv_k2, used if ws too small for tmp.
// ---------------------------------------------------------------------------
__global__ __launch_bounds__(64, 2)
void conv_k2_fb(const int* __restrict__ nidx, const void* __restrict__ maskp,
                const int* __restrict__ flagp,
                const unsigned short* __restrict__ out1,
                const unsigned short* __restrict__ W2p,
                const float* __restrict__ g2, const float* __restrict__ b2,
                const float* __restrict__ x, float* __restrict__ outp) {
    __shared__ int s_gidx[64 * KOFF];

    int t = threadIdx.x;
    int nb = blockIdx.x * 64;
    int mflag = *flagp;
    stage_gidx64(s_gidx, nidx, maskp, mflag, nb, t);
    __syncthreads();

    int lane = t & 63;
    int mrow = lane & 15, quad = lane >> 4;
    const unsigned short* a_base = out1 + quad * 8;
    const int* gp0 = &s_gidx[(0 * 16 + mrow) * KOFF];
    const int* gp1 = &s_gidx[(1 * 16 + mrow) * KOFF];
    const int* gp2 = &s_gidx[(2 * 16 + mrow) * KOFF];
    const int* gp3 = &s_gidx[(3 * 16 + mrow) * KOFF];

    f32x4 acc[4][2] = {};
    bf16x8 a[2][4][4], b[2][8];

    {
        const unsigned short* wb = W2p + (lane << 3);
#pragma unroll
        for (int f = 0; f < 8; ++f)
            b[0][f] = *reinterpret_cast<const bf16x8*>(wb + ((f * 64) << 3));
        int gg[4] = { gp0[0], gp1[0], gp2[0], gp3[0] };
#pragma unroll
        for (int rt = 0; rt < 4; ++rt) {
#pragma unroll
            for (int kc = 0; kc < 4; ++kc) a[0][rt][kc] = bf16x8{};
            if (gg[rt] >= 0) {
#pragma unroll
                for (int kc = 0; kc < 4; ++kc)
                    a[0][rt][kc] = *reinterpret_cast<const bf16x8*>(a_base + (size_t)gg[rt] * 128 + kc * 32);
            }
        }
    }

#pragma unroll
    for (int k = 0; k < KOFF; ++k) {
        int cur = k & 1, nxt = cur ^ 1;
        if (k + 1 < KOFF) {
            const unsigned short* wb = W2p + ((((k + 1) * 8) * 64 + lane) << 3);
#pragma unroll
            for (int f = 0; f < 8; ++f)
                b[nxt][f] = *reinterpret_cast<const bf16x8*>(wb + ((f * 64) << 3));
            int gg[4] = { gp0[k + 1], gp1[k + 1], gp2[k + 1], gp3[k + 1] };
#pragma unroll
            for (int rt = 0; rt < 4; ++rt) {
#pragma unroll
                for (int kc = 0; kc < 4; ++kc) a[nxt][rt][kc] = bf16x8{};
                if (gg[rt] >= 0) {
#pragma unroll
                    for (int kc = 0; kc < 4; ++kc)
                        a[nxt][rt][kc] = *reinterpret_cast<const bf16x8*>(a_base + (size_t)gg[rt] * 128 + kc * 32);
                }
            }
        }
#pragma unroll
        for (int rt = 0; rt < 4; ++rt)
#pragma unroll
            for (int kc = 0; kc < 4; ++kc) {
                acc[rt][0] = __builtin_amdgcn_mfma_f32_16x16x32_bf16(a[cur][rt][kc], b[cur][kc * 2 + 0], acc[rt][0], 0, 0, 0);
                acc[rt][1] = __builtin_amdgcn_mfma_f32_16x16x32_bf16(a[cur][rt][kc], b[cur][kc * 2 + 1], acc[rt][1], 0, 0, 0);
            }
    }

    float gv0 = g2[mrow], gv1 = g2[mrow + 16];
    float bv0 = b2[mrow], bv1 = b2[mrow + 16];
#pragma unroll
    for (int rt = 0; rt < 4; ++rt) {
        int n_base = nb + rt * 16 + quad * 4;
#pragma unroll
        for (int r = 0; r < 4; ++r) {
            float v0 = acc[rt][0][r], v1 = acc[rt][1][r];
            float s = v0 + v1, s2 = v0 * v0 + v1 * v1;
#pragma unroll
            for (int m = 1; m <= 8; m <<= 1) {
                s  += __shfl_xor(s,  m, 16);
                s2 += __shfl_xor(s2, m, 16);
            }
            float mu = s * (1.f / 32.f);
            float rs = rsqrtf(s2 * (1.f / 32.f) - mu * mu + 1e-6f);
            int n = n_base + r;
            if (n < NPTS) {
                float y0 = (v0 - mu) * rs * gv0 + bv0 + x[n * 32 + mrow];
                float y1 = (v1 - mu) * rs * gv1 + bv1 + x[n * 32 + mrow + 16];
                outp[n * 32 + mrow]      = gelu_erf(y0);
                outp[n * 32 + mrow + 16] = gelu_erf(y1);
            }
        }
    }
}

// ---------------------------------------------------------------------------
extern "C" void kernel_launch(void* const* d_in, const int* in_sizes, int n_in,
                              void* d_out, int out_size, void* d_ws, size_t ws_size,
                              hipStream_t stream) {
    const float* x    = (const float*)d_in[0];
    const int*   nidx = (const int*)d_in[1];
    const void*  maskp = d_in[2];
    const float* Wc = (const float*)d_in[3];
    const float* g0 = (const float*)d_in[4];
    const float* b0 = (const float*)d_in[5];
    const float* W1 = (const float*)d_in[6];
    const float* g1 = (const float*)d_in[7];
    const float* b1 = (const float*)d_in[8];
    const float* W2 = (const float*)d_in[9];
    const float* g2 = (const float*)d_in[10];
    const float* b2 = (const float*)d_in[11];

    char* ws = (char*)d_ws;
    unsigned short* out0 = (unsigned short*)ws;                      // 6,400,000
    unsigned short* out1 = (unsigned short*)(ws + 6400000);          // 25,600,000
    unsigned short* W1p  = (unsigned short*)(ws + 32000000);         // 221,184
    unsigned short* W2p  = (unsigned short*)(ws + 32221184);         // 221,184
    int* flagp           = (int*)(ws + 32442368);                    // 4 (+pad)
    unsigned short* tmp  = (unsigned short*)(ws + 32442432);         // 172,800,000
    const size_t NEED_TMP = 32442432UL + (size_t)KOFF * NPTS * 32 * 2;

    repack_kernel<<<432, 256, 0, stream>>>(W1, W2, maskp, W1p, W2p, flagp);
    conv1_ln_gelu<<<NPTS / 8, 256, 0, stream>>>(x, Wc, g0, b0, out0);
    conv_k1<<<(NPTS + 63) / 64, 64, 0, stream>>>(nidx, maskp, flagp, out0, W1p, g1, b1, out1);
    if (ws_size >= NEED_TMP) {
        gemm_tmp<<<(NPTS + 63) / 64, 64, 0, stream>>>(out1, W2p, tmp);
        gather_sum<<<(NPTS + 63) / 64, 256, 0, stream>>>(nidx, maskp, flagp, tmp, g2, b2, x, (float*)d_out);
    } else {
        conv_k2_fb<<<(NPTS + 63) / 64, 64, 0, stream>>>(nidx, maskp, flagp, out1, W2p, g2, b2, x, (float*)d_out);
    }
}

// Round 9
// 269.670 us; speedup vs baseline: 1.9313x; 1.0302x over previous
//
#include <hip/hip_runtime.h>
#include <hip/hip_bf16.h>
#include <math.h>

#define NPTS 100000
#define KOFF 27

typedef __attribute__((ext_vector_type(8))) __bf16 bf16x8;
typedef __attribute__((ext_vector_type(4))) float f32x4;

__device__ __forceinline__ unsigned short f2bf(float f) {
    unsigned int u = __float_as_uint(f);
    u += 0x7fffu + ((u >> 16) & 1u);   // RNE
    return (unsigned short)(u >> 16);
}

__device__ __forceinline__ float gelu_erf(float v) {
    return 0.5f * v * (1.0f + erff(v * 0.70710678118654752f));
}

// ---------------------------------------------------------------------------
// Kernel 0: repack W1 -> W1p (MFMA B-frag order), W2 -> W2p (frag order, for
// fallback) and W2 -> W2q (frag order with INTERLEAVED columns: frag position
// (ct,nn) holds actual column 2*nn+ct, so gemm_tmp's two per-lane outputs are
// adjacent columns and pack into one dword store). Also sniff mask dtype.
// ---------------------------------------------------------------------------
__global__ __launch_bounds__(256)
void repack_kernel(const float* __restrict__ W1, const float* __restrict__ W2,
                   const void* __restrict__ maskp,
                   unsigned short* __restrict__ W1p,
                   unsigned short* __restrict__ W2p,
                   unsigned short* __restrict__ W2q,
                   int* __restrict__ flagp) {
    int o = blockIdx.x * 256 + threadIdx.x;
    if (o == 0) {
        const unsigned int* mw = (const unsigned int*)maskp;
        int f = 0;
        for (int i = 0; i < 64; ++i) f |= (mw[i] > 1u) ? 1 : 0;
        *flagp = f;   // 1 => byte/bool mask, 0 => int32 mask
    }
    if (o < KOFF * 32 * 128) {
        int j = o & 7, lane = (o >> 3) & 63;
        int quad = lane >> 4, nn = lane & 15;
        int ct1 = (o >> 9) & 7, k1 = o >> 12;
        int kk1 = quad * 8 + j;
        W1p[o] = f2bf(W1[(k1 * 32 + kk1) * 128 + (ct1 * 16 + nn)]);
        int ct2 = (o >> 9) & 1, kc2 = (o >> 10) & 3, k2 = o >> 12;
        int kk2 = kc2 * 32 + quad * 8 + j;
        W2p[o] = f2bf(W2[(k2 * 128 + kk2) * 32 + (ct2 * 16 + nn)]);
        W2q[o] = f2bf(W2[(k2 * 128 + kk2) * 32 + (2 * nn + ct2)]);
    }
}

// ---------------------------------------------------------------------------
// Kernel 1: out0 = bf16( gelu( LN( x @ W_conv ) ) )   [N,32]
// ---------------------------------------------------------------------------
__global__ __launch_bounds__(256)
void conv1_ln_gelu(const float* __restrict__ x, const float* __restrict__ Wc,
                   const float* __restrict__ g0, const float* __restrict__ b0,
                   unsigned short* __restrict__ out0) {
    __shared__ float xs[256];
    __shared__ float wc[1024];
    int t = threadIdx.x;
    int nb = blockIdx.x * 8;
    xs[t] = x[nb * 32 + t];
    for (int i = t; i < 1024; i += 256) wc[i] = Wc[i];
    __syncthreads();
    int r = t >> 5, d = t & 31;
    const float* xr = &xs[r * 32];
    float v = 0.f;
#pragma unroll
    for (int c = 0; c < 32; ++c) v = fmaf(xr[c], wc[c * 32 + d], v);
    float s = v, s2 = v * v;
#pragma unroll
    for (int m = 16; m >= 1; m >>= 1) {
        s  += __shfl_xor(s,  m, 32);
        s2 += __shfl_xor(s2, m, 32);
    }
    float mu  = s * (1.f / 32.f);
    float var = s2 * (1.f / 32.f) - mu * mu;
    float y = (v - mu) * rsqrtf(var + 1e-6f) * g0[d] + b0[d];
    out0[nb * 32 + t] = f2bf(gelu_erf(y));
}

// ---------------------------------------------------------------------------
// Stage gather indices into LDS (-1 = masked/tail, skip load).
// ---------------------------------------------------------------------------
__device__ __forceinline__ void stage_gidx64(int* s_gidx, const int* nidx,
                                             const void* maskp, int mflag,
                                             int nb, int t) {
    int cnt = (NPTS - nb < 64 ? NPTS - nb : 64) * KOFF;
    for (int i = t; i < 64 * KOFF; i += 64) {
        int g = -1;
        if (i < cnt) {
            int gi = nidx[nb * KOFF + i];
            int m = mflag ? (int)((const unsigned char*)maskp)[nb * KOFF + i]
                          : ((const int*)maskp)[nb * KOFF + i];
            g = m ? gi : -1;
        }
        s_gidx[i] = g;
    }
}

// ---------------------------------------------------------------------------
// Kernel 2: out1 = bf16( gelu( LN( sparse_conv(out0, W1) ) ) )   [N,128]
// NEW shape: 32 rows/wave, 1-wave blocks (grid 3125 = 12.2 blocks/CU; acc
// halves to 64 AGPR -> ~180 unified regs, 2 waves/SIMD cap -> 8 waves/CU
// effective, was 6.1). Distance-2 rings (3 slots) for BOTH A and B.
// ---------------------------------------------------------------------------
__global__ __launch_bounds__(64, 2)
void conv_k1(const int* __restrict__ nidx, const void* __restrict__ maskp,
             const int* __restrict__ flagp,
             const unsigned short* __restrict__ out0,
             const unsigned short* __restrict__ W1p,
             const float* __restrict__ g1, const float* __restrict__ b1,
             unsigned short* __restrict__ out1) {
    __shared__ int s_gidx[32 * KOFF];

    int t = threadIdx.x;
    int nb = blockIdx.x * 32;           // 100000 = 32*3125, no tail
    int mflag = *flagp;
    {
        for (int i = t; i < 32 * KOFF; i += 64) {
            int gi = nidx[nb * KOFF + i];
            int m = mflag ? (int)((const unsigned char*)maskp)[nb * KOFF + i]
                          : ((const int*)maskp)[nb * KOFF + i];
            s_gidx[i] = m ? gi : -1;
        }
    }
    __syncthreads();

    int lane = t & 63;
    int mrow = lane & 15, quad = lane >> 4;
    const unsigned short* a_base = out0 + quad * 8;
    const int* gp0 = &s_gidx[(0 * 16 + mrow) * KOFF];
    const int* gp1 = &s_gidx[(1 * 16 + mrow) * KOFF];

    f32x4 acc[2][8] = {};
    bf16x8 a[3][2], b[3][8];

    // prologue, oldest-first: B(0),A(0),B(1),A(1)
#pragma unroll
    for (int d = 0; d < 2; ++d) {
        const unsigned short* wb = W1p + (((d * 8) * 64 + lane) << 3);
#pragma unroll
        for (int ct = 0; ct < 8; ++ct)
            b[d][ct] = *reinterpret_cast<const bf16x8*>(wb + ((ct * 64) << 3));
        int g0 = gp0[d], g1i = gp1[d];
        a[d][0] = bf16x8{}; if (g0  >= 0) a[d][0] = *reinterpret_cast<const bf16x8*>(a_base + g0  * 32);
        a[d][1] = bf16x8{}; if (g1i >= 0) a[d][1] = *reinterpret_cast<const bf16x8*>(a_base + g1i * 32);
    }

#pragma unroll
    for (int k = 0; k < KOFF; ++k) {
        if (k + 2 < KOFF) {   // B(k+2) then A(k+2)
            int s = (k + 2) % 3;
            const unsigned short* wb = W1p + ((((k + 2) * 8) * 64 + lane) << 3);
#pragma unroll
            for (int ct = 0; ct < 8; ++ct)
                b[s][ct] = *reinterpret_cast<const bf16x8*>(wb + ((ct * 64) << 3));
            int g0 = gp0[k + 2], g1i = gp1[k + 2];
            a[s][0] = bf16x8{}; if (g0  >= 0) a[s][0] = *reinterpret_cast<const bf16x8*>(a_base + g0  * 32);
            a[s][1] = bf16x8{}; if (g1i >= 0) a[s][1] = *reinterpret_cast<const bf16x8*>(a_base + g1i * 32);
        }
#pragma unroll
        for (int rt = 0; rt < 2; ++rt)
#pragma unroll
            for (int ct = 0; ct < 8; ++ct)
                acc[rt][ct] = __builtin_amdgcn_mfma_f32_16x16x32_bf16(a[k % 3][rt], b[k % 3][ct], acc[rt][ct], 0, 0, 0);
    }

    // Epilogue: LN(128) + GELU in-register.
    float gv[8], bv[8];
#pragma unroll
    for (int ct = 0; ct < 8; ++ct) {
        gv[ct] = g1[ct * 16 + mrow];
        bv[ct] = b1[ct * 16 + mrow];
    }
#pragma unroll
    for (int rt = 0; rt < 2; ++rt) {
        int n_base = nb + rt * 16 + quad * 4;
#pragma unroll
        for (int r = 0; r < 4; ++r) {
            float s = 0.f, s2 = 0.f;
#pragma unroll
            for (int ct = 0; ct < 8; ++ct) { float v = acc[rt][ct][r]; s += v; s2 += v * v; }
#pragma unroll
            for (int m = 1; m <= 8; m <<= 1) {
                s  += __shfl_xor(s,  m, 16);
                s2 += __shfl_xor(s2, m, 16);
            }
            float mu = s * (1.f / 128.f);
            float rs = rsqrtf(s2 * (1.f / 128.f) - mu * mu + 1e-6f);
            int n = n_base + r;
#pragma unroll
            for (int ct = 0; ct < 8; ++ct) {
                float y = (acc[rt][ct][r] - mu) * rs * gv[ct] + bv[ct];
                out1[n * 128 + ct * 16 + mrow] = f2bf(gelu_erf(y));
            }
        }
    }
}

// ---------------------------------------------------------------------------
// Kernel 3a: tmp[k][n][32] = bf16( out1[n,:] @ W2[k] )  — DENSE, no gathers.
// Uses W2q (interleaved cols): lane m's two outputs are actual cols 2m,2m+1
// -> packed dword store, 4 full 64B segments per store instr.
// ---------------------------------------------------------------------------
__global__ __launch_bounds__(64, 2)
void gemm_tmp(const unsigned short* __restrict__ out1,
              const unsigned short* __restrict__ W2q,
              unsigned short* __restrict__ tmp) {
    int t = threadIdx.x;
    int nb = blockIdx.x * 64;
    int mrow = t & 15, quad = t >> 4;

    bf16x8 a[4][4];
#pragma unroll
    for (int rt = 0; rt < 4; ++rt) {
        int n = nb + rt * 16 + mrow;
        bool ok = (n < NPTS);
#pragma unroll
        for (int kc = 0; kc < 4; ++kc) {
            a[rt][kc] = bf16x8{};
            if (ok)
                a[rt][kc] = *reinterpret_cast<const bf16x8*>(out1 + (size_t)n * 128 + kc * 32 + quad * 8);
        }
    }
    bf16x8 b[2][8];
    {
        const unsigned short* wb = W2q + (t << 3);
#pragma unroll
        for (int f = 0; f < 8; ++f)
            b[0][f] = *reinterpret_cast<const bf16x8*>(wb + ((f * 64) << 3));
    }

#pragma unroll
    for (int k = 0; k < KOFF; ++k) {
        int cur = k & 1, nxt = cur ^ 1;
        if (k + 1 < KOFF) {
            const unsigned short* wb = W2q + ((((k + 1) * 8) * 64 + t) << 3);
#pragma unroll
            for (int f = 0; f < 8; ++f)
                b[nxt][f] = *reinterpret_cast<const bf16x8*>(wb + ((f * 64) << 3));
        }
        f32x4 acc[4][2] = {};
#pragma unroll
        for (int rt = 0; rt < 4; ++rt)
#pragma unroll
            for (int kc = 0; kc < 4; ++kc) {
                acc[rt][0] = __builtin_amdgcn_mfma_f32_16x16x32_bf16(a[rt][kc], b[cur][kc * 2 + 0], acc[rt][0], 0, 0, 0);
                acc[rt][1] = __builtin_amdgcn_mfma_f32_16x16x32_bf16(a[rt][kc], b[cur][kc * 2 + 1], acc[rt][1], 0, 0, 0);
            }
        unsigned int* tk32 = (unsigned int*)(tmp + (size_t)k * NPTS * 32);
#pragma unroll
        for (int rt = 0; rt < 4; ++rt) {
            int n0 = nb + rt * 16 + quad * 4;
#pragma unroll
            for (int r = 0; r < 4; ++r) {
                int n = n0 + r;
                if (n < NPTS) {
                    unsigned int pk = (unsigned int)f2bf(acc[rt][0][r])
                                    | ((unsigned int)f2bf(acc[rt][1][r]) << 16);
                    tk32[(size_t)n * 16 + mrow] = pk;   // actual cols 2m,2m+1
                }
            }
        }
    }
}

// ---------------------------------------------------------------------------
// Kernel 3b: out = gelu( LN( Σ_k mask·tmp[k][idx[n,k]] ) + x )   [N,32] fp32
// tmp rows are in actual column order -> unchanged logic. Ring depth 4.
// ---------------------------------------------------------------------------
__global__ __launch_bounds__(256)
void gather_sum(const int* __restrict__ nidx, const void* __restrict__ maskp,
                const int* __restrict__ flagp,
                const unsigned short* __restrict__ tmp,
                const float* __restrict__ g2, const float* __restrict__ b2,
                const float* __restrict__ x, float* __restrict__ outp) {
    __shared__ int s_gidx[64 * KOFF];
    int t = threadIdx.x;
    int nb = blockIdx.x * 64;
    int mflag = *flagp;
    int cnt = (NPTS - nb < 64 ? NPTS - nb : 64) * KOFF;
    for (int i = t; i < 64 * KOFF; i += 256) {
        int g = -1;
        if (i < cnt) {
            int gi = nidx[nb * KOFF + i];
            int m = mflag ? (int)((const unsigned char*)maskp)[nb * KOFF + i]
                          : ((const int*)maskp)[nb * KOFF + i];
            g = m ? gi : -1;
        }
        s_gidx[i] = g;
    }
    __syncthreads();

    int rl = t >> 2, q = t & 3;
    const int* gp = &s_gidx[rl * KOFF];
    const unsigned short* tq = tmp + q * 8;

    float acc[8] = {};
    uint4 ring[4];
#pragma unroll
    for (int d = 0; d < 4; ++d) {
        int g = gp[d];
        ring[d] = uint4{0u, 0u, 0u, 0u};
        if (g >= 0)
            ring[d] = *reinterpret_cast<const uint4*>(tq + ((size_t)d * NPTS + g) * 32);
    }
#pragma unroll
    for (int k = 0; k < KOFF; ++k) {
        uint4 v = ring[k & 3];
        if (k + 4 < KOFF) {
            int g = gp[k + 4];
            ring[k & 3] = uint4{0u, 0u, 0u, 0u};
            if (g >= 0)
                ring[k & 3] = *reinterpret_cast<const uint4*>(tq + ((size_t)(k + 4) * NPTS + g) * 32);
        }
        unsigned int w0 = v.x, w1 = v.y, w2 = v.z, w3 = v.w;
        acc[0] += __uint_as_float(w0 << 16);
        acc[1] += __uint_as_float(w0 & 0xffff0000u);
        acc[2] += __uint_as_float(w1 << 16);
        acc[3] += __uint_as_float(w1 & 0xffff0000u);
        acc[4] += __uint_as_float(w2 << 16);
        acc[5] += __uint_as_float(w2 & 0xffff0000u);
        acc[6] += __uint_as_float(w3 << 16);
        acc[7] += __uint_as_float(w3 & 0xffff0000u);
    }

    float s = 0.f, s2 = 0.f;
#pragma unroll
    for (int j = 0; j < 8; ++j) { s += acc[j]; s2 += acc[j] * acc[j]; }
    s += __shfl_xor(s, 1); s2 += __shfl_xor(s2, 1);
    s += __shfl_xor(s, 2); s2 += __shfl_xor(s2, 2);
    float mu = s * (1.f / 32.f);
    float rs = rsqrtf(s2 * (1.f / 32.f) - mu * mu + 1e-6f);

    int n = nb + rl;
    if (n < NPTS) {
        float o[8];
#pragma unroll
        for (int j = 0; j < 8; ++j) {
            int c = q * 8 + j;
            float y = (acc[j] - mu) * rs * g2[c] + b2[c] + x[n * 32 + c];
            o[j] = gelu_erf(y);
        }
        *reinterpret_cast<float4*>(outp + n * 32 + q * 8)     = make_float4(o[0], o[1], o[2], o[3]);
        *reinterpret_cast<float4*>(outp + n * 32 + q * 8 + 4) = make_float4(o[4], o[5], o[6], o[7]);
    }
}

// ---------------------------------------------------------------------------
// Fallback Kernel 3 (r4): gather-GEMM conv_k2 (uses W2p), if ws too small.
// ---------------------------------------------------------------------------
__global__ __launch_bounds__(64, 2)
void conv_k2_fb(const int* __restrict__ nidx, const void* __restrict__ maskp,
                const int* __restrict__ flagp,
                const unsigned short* __restrict__ out1,
                const unsigned short* __restrict__ W2p,
                const float* __restrict__ g2, const float* __restrict__ b2,
                const float* __restrict__ x, float* __restrict__ outp) {
    __shared__ int s_gidx[64 * KOFF];

    int t = threadIdx.x;
    int nb = blockIdx.x * 64;
    int mflag = *flagp;
    stage_gidx64(s_gidx, nidx, maskp, mflag, nb, t);
    __syncthreads();

    int lane = t & 63;
    int mrow = lane & 15, quad = lane >> 4;
    const unsigned short* a_base = out1 + quad * 8;
    const int* gp0 = &s_gidx[(0 * 16 + mrow) * KOFF];
    const int* gp1 = &s_gidx[(1 * 16 + mrow) * KOFF];
    const int* gp2 = &s_gidx[(2 * 16 + mrow) * KOFF];
    const int* gp3 = &s_gidx[(3 * 16 + mrow) * KOFF];

    f32x4 acc[4][2] = {};
    bf16x8 a[2][4][4], b[2][8];

    {
        const unsigned short* wb = W2p + (lane << 3);
#pragma unroll
        for (int f = 0; f < 8; ++f)
            b[0][f] = *reinterpret_cast<const bf16x8*>(wb + ((f * 64) << 3));
        int gg[4] = { gp0[0], gp1[0], gp2[0], gp3[0] };
#pragma unroll
        for (int rt = 0; rt < 4; ++rt) {
#pragma unroll
            for (int kc = 0; kc < 4; ++kc) a[0][rt][kc] = bf16x8{};
            if (gg[rt] >= 0) {
#pragma unroll
                for (int kc = 0; kc < 4; ++kc)
                    a[0][rt][kc] = *reinterpret_cast<const bf16x8*>(a_base + (size_t)gg[rt] * 128 + kc * 32);
            }
        }
    }

#pragma unroll
    for (int k = 0; k < KOFF; ++k) {
        int cur = k & 1, nxt = cur ^ 1;
        if (k + 1 < KOFF) {
            const unsigned short* wb = W2p + ((((k + 1) * 8) * 64 + lane) << 3);
#pragma unroll
            for (int f = 0; f < 8; ++f)
                b[nxt][f] = *reinterpret_cast<const bf16x8*>(wb + ((f * 64) << 3));
            int gg[4] = { gp0[k + 1], gp1[k + 1], gp2[k + 1], gp3[k + 1] };
#pragma unroll
            for (int rt = 0; rt < 4; ++rt) {
#pragma unroll
                for (int kc = 0; kc < 4; ++kc) a[nxt][rt][kc] = bf16x8{};
                if (gg[rt] >= 0) {
#pragma unroll
                    for (int kc = 0; kc < 4; ++kc)
                        a[nxt][rt][kc] = *reinterpret_cast<const bf16x8*>(a_base + (size_t)gg[rt] * 128 + kc * 32);
                }
            }
        }
#pragma unroll
        for (int rt = 0; rt < 4; ++rt)
#pragma unroll
            for (int kc = 0; kc < 4; ++kc) {
                acc[rt][0] = __builtin_amdgcn_mfma_f32_16x16x32_bf16(a[cur][rt][kc], b[cur][kc * 2 + 0], acc[rt][0], 0, 0, 0);
                acc[rt][1] = __builtin_amdgcn_mfma_f32_16x16x32_bf16(a[cur][rt][kc], b[cur][kc * 2 + 1], acc[rt][1], 0, 0, 0);
            }
    }

    float gv0 = g2[mrow], gv1 = g2[mrow + 16];
    float bv0 = b2[mrow], bv1 = b2[mrow + 16];
#pragma unroll
    for (int rt = 0; rt < 4; ++rt) {
        int n_base = nb + rt * 16 + quad * 4;
#pragma unroll
        for (int r = 0; r < 4; ++r) {
            float v0 = acc[rt][0][r], v1 = acc[rt][1][r];
            float s = v0 + v1, s2 = v0 * v0 + v1 * v1;
#pragma unroll
            for (int m = 1; m <= 8; m <<= 1) {
                s  += __shfl_xor(s,  m, 16);
                s2 += __shfl_xor(s2, m, 16);
            }
            float mu = s * (1.f / 32.f);
            float rs = rsqrtf(s2 * (1.f / 32.f) - mu * mu + 1e-6f);
            int n = n_base + r;
            if (n < NPTS) {
                float y0 = (v0 - mu) * rs * gv0 + bv0 + x[n * 32 + mrow];
                float y1 = (v1 - mu) * rs * gv1 + bv1 + x[n * 32 + mrow + 16];
                outp[n * 32 + mrow]      = gelu_erf(y0);
                outp[n * 32 + mrow + 16] = gelu_erf(y1);
            }
        }
    }
}

// ---------------------------------------------------------------------------
extern "C" void kernel_launch(void* const* d_in, const int* in_sizes, int n_in,
                              void* d_out, int out_size, void* d_ws, size_t ws_size,
                              hipStream_t stream) {
    const float* x    = (const float*)d_in[0];
    const int*   nidx = (const int*)d_in[1];
    const void*  maskp = d_in[2];
    const float* Wc = (const float*)d_in[3];
    const float* g0 = (const float*)d_in[4];
    const float* b0 = (const float*)d_in[5];
    const float* W1 = (const float*)d_in[6];
    const float* g1 = (const float*)d_in[7];
    const float* b1 = (const float*)d_in[8];
    const float* W2 = (const float*)d_in[9];
    const float* g2 = (const float*)d_in[10];
    const float* b2 = (const float*)d_in[11];

    char* ws = (char*)d_ws;
    unsigned short* out0 = (unsigned short*)ws;                      // 6,400,000
    unsigned short* out1 = (unsigned short*)(ws + 6400000);          // 25,600,000
    unsigned short* W1p  = (unsigned short*)(ws + 32000000);         // 221,184
    unsigned short* W2p  = (unsigned short*)(ws + 32221184);         // 221,184
    unsigned short* W2q  = (unsigned short*)(ws + 32442368);         // 221,184
    int* flagp           = (int*)(ws + 32663552);                    // 4 (+pad)
    unsigned short* tmp  = (unsigned short*)(ws + 32663616);         // 172,800,000
    const size_t NEED_TMP = 32663616UL + (size_t)KOFF * NPTS * 32 * 2;

    repack_kernel<<<432, 256, 0, stream>>>(W1, W2, maskp, W1p, W2p, W2q, flagp);
    conv1_ln_gelu<<<NPTS / 8, 256, 0, stream>>>(x, Wc, g0, b0, out0);
    conv_k1<<<NPTS / 32, 64, 0, stream>>>(nidx, maskp, flagp, out0, W1p, g1, b1, out1);
    if (ws_size >= NEED_TMP) {
        gemm_tmp<<<(NPTS + 63) / 64, 64, 0, stream>>>(out1, W2q, tmp);
        gather_sum<<<(NPTS + 63) / 64, 256, 0, stream>>>(nidx, maskp, flagp, tmp, g2, b2, x, (float*)d_out);
    } else {
        conv_k2_fb<<<(NPTS + 63) / 64, 64, 0, stream>>>(nidx, maskp, flagp, out1, W2p, g2, b2, x, (float*)d_out);
    }
}